// Round 11
// baseline (214.615 us; speedup 1.0000x reference)
//
#include <hip/hip_runtime.h>

// N=1e6, D1=D2=16, NC=64 outer, NCPC=8 inner.
// R11 = R10 EXACTLY, except the grid is doubled with blockIdx%nb remapping so the
// kernel dispatch (~128us) outranks the harness's ~74us fills and finally surfaces
// in top-5 WITH counters. Duplicate blocks write identical values (benign race).
// DIAGNOSTIC ROUND: dur_us will be ~256 by design; R10 (192.4) is the keeper.
constexpr int D = 16;
constexpr int NC = 64;
constexpr int NCPC = 8;
constexpr int OSTRIDE = NCPC * D + 4;   // 132 floats
constexpr int BLOCK = 256;              // 4 waves/block
constexpr int NPT = 2;                  // 512 pts/block

typedef __attribute__((ext_vector_type(8)))  short short8;
typedef __attribute__((ext_vector_type(16))) float f32x16;

static __device__ __forceinline__ unsigned f2bf(float f) {   // RNE fp32->bf16 bits
    unsigned u = __float_as_uint(f);
    u += 0x7FFFu + ((u >> 16) & 1u);
    return u >> 16;
}
static __device__ __forceinline__ float bf2f(unsigned h) {
    return __uint_as_float(h << 16);
}

// 3-way bf16 split of (-2 * x) for one 8-element k-slice.
static __device__ __forceinline__ void conv_pt(float4 w0, float4 w1,
                                               short8* bh, short8* bm, short8* bl) {
    float vv[8] = {w0.x,w0.y,w0.z,w0.w, w1.x,w1.y,w1.z,w1.w};
    #pragma unroll
    for (int j = 0; j < 8; ++j) {
        float v = -2.0f * vv[j];           // exact (power of two)
        unsigned h = f2bf(v); float r1 = v - bf2f(h);
        unsigned m = f2bf(r1); r1 = r1 - bf2f(m);
        unsigned l2 = f2bf(r1);
        (*bh)[j] = (short)h; (*bm)[j] = (short)m; (*bl)[j] = (short)l2;
    }
}

// MFMA distance + within-lane argmin + cross-half merge for one 32-point tile.
static __device__ __forceinline__ int mfma_scan(const short8* a_h, const short8* a_m,
                                                const short8* a_l,
                                                short8 bh, short8 bm, short8 bl,
                                                const float* s_onorm, int hi4) {
    float bestd = 3.4e38f; int bc = 0;
    #pragma unroll
    for (int tc = 0; tc < 2; ++tc) {
        f32x16 acc;
        #pragma unroll
        for (int g = 0; g < 4; ++g) {       // acc init = outer norms (broadcast ds_read)
            float4 nn = *(const float4*)&s_onorm[tc * 32 + g * 8 + hi4];
            acc[g*4+0] = nn.x; acc[g*4+1] = nn.y; acc[g*4+2] = nn.z; acc[g*4+3] = nn.w;
        }
        acc = __builtin_amdgcn_mfma_f32_32x32x16_bf16(a_h[tc], bh, acc, 0,0,0);
        acc = __builtin_amdgcn_mfma_f32_32x32x16_bf16(a_h[tc], bm, acc, 0,0,0);
        acc = __builtin_amdgcn_mfma_f32_32x32x16_bf16(a_m[tc], bh, acc, 0,0,0);
        acc = __builtin_amdgcn_mfma_f32_32x32x16_bf16(a_h[tc], bl, acc, 0,0,0);
        acc = __builtin_amdgcn_mfma_f32_32x32x16_bf16(a_m[tc], bm, acc, 0,0,0);
        acc = __builtin_amdgcn_mfma_f32_32x32x16_bf16(a_l[tc], bh, acc, 0,0,0);
        #pragma unroll
        for (int r = 0; r < 16; ++r) {      // increasing-index scan, strict <
            float d = acc[r];
            int  c = tc * 32 + (r & 3) + 8 * (r >> 2);
            if (d < bestd) { bestd = d; bc = c; }
        }
    }
    int bestc = bc + hi4;
    int lane = (int)(threadIdx.x & 63);
    int pidx = (lane ^ 32) << 2;
    float od = __int_as_float(
        __builtin_amdgcn_ds_bpermute(pidx, __float_as_int(bestd)));
    int   oc = __builtin_amdgcn_ds_bpermute(pidx, bestc);
    if (od < bestd || (od == bestd && oc < bestc)) bestc = oc;
    return bestc;
}

// Inner argmin over bo's 8 sub-centers (LDS gather). Unchanged arithmetic.
static __device__ __forceinline__ int inner_argmin(const float* s_ci,
                                                   const float* s_inorm,
                                                   int bo, const float* x2) {
    const float* cb = s_ci + bo * OSTRIDE;
    const float* nb = s_inorm + bo * 9;
    float bestd2 = 3.4e38f;
    int bk = 0;
    #pragma unroll
    for (int k = 0; k < NCPC; ++k) {
        float4 e0 = *(const float4*)&cb[k * D + 0];
        float4 e1 = *(const float4*)&cb[k * D + 4];
        float4 e2 = *(const float4*)&cb[k * D + 8];
        float4 e3 = *(const float4*)&cb[k * D + 12];
        float dot = 0.f;
        dot = fmaf(x2[0],  e0.x, dot); dot = fmaf(x2[1],  e0.y, dot);
        dot = fmaf(x2[2],  e0.z, dot); dot = fmaf(x2[3],  e0.w, dot);
        dot = fmaf(x2[4],  e1.x, dot); dot = fmaf(x2[5],  e1.y, dot);
        dot = fmaf(x2[6],  e1.z, dot); dot = fmaf(x2[7],  e1.w, dot);
        dot = fmaf(x2[8],  e2.x, dot); dot = fmaf(x2[9],  e2.y, dot);
        dot = fmaf(x2[10], e2.z, dot); dot = fmaf(x2[11], e2.w, dot);
        dot = fmaf(x2[12], e3.x, dot); dot = fmaf(x2[13], e3.y, dot);
        dot = fmaf(x2[14], e3.z, dot); dot = fmaf(x2[15], e3.w, dot);
        float d2v = fmaf(-2.f, dot, nb[k]);
        if (d2v < bestd2) { bestd2 = d2v; bk = k; }
    }
    return bk;
}

__global__ __launch_bounds__(BLOCK, 4)   // 4 blocks/CU -> VGPR cap 128, 16 waves/CU
void cluster_kernel(const float* __restrict__ x,
                    const float* __restrict__ co,
                    const float* __restrict__ ci,
                    int* __restrict__ out, int n, int nb)
{
    __shared__ __align__(16) float s_ci[NC * OSTRIDE];   // 33792 B
    __shared__ __align__(16) float s_onorm[NC];          // 256 B
    __shared__ float s_inorm[NC * 9];                    // 2304 B

    const int t    = threadIdx.x;
    const int lane = t & 63;
    const int wave = t >> 6;
    int vb = blockIdx.x;                 // duplicate-grid remap (diagnostic)
    if (vb >= nb) vb -= nb;

    // ---- Stage inner centers (2048 float4) ----
    const float4* ci4 = (const float4*)ci;
    #pragma unroll
    for (int i = 0; i < 8; ++i) {
        int idx = t + i * BLOCK;
        int o = idx >> 5, f = idx & 31;
        float4 v = ci4[idx];
        *(float4*)&s_ci[o * OSTRIDE + f * 4] = v;
    }
    // ---- 512 inner norms ----
    #pragma unroll
    for (int ii = 0; ii < 2; ++ii) {
        int i = t + ii * BLOCK;
        const float* src = ci + i * D;
        float s = 0.f;
        #pragma unroll
        for (int k = 0; k < D; ++k) s = fmaf(src[k], src[k], s);
        s_inorm[(i >> 3) * 9 + (i & 7)] = s;
    }
    // ---- 64 outer norms -> LDS ----
    if (t < NC) {
        const float* c = co + t * D;
        float s = 0.f;
        #pragma unroll
        for (int k = 0; k < D; ++k) s = fmaf(c[k], c[k], s);
        s_onorm[t] = s;
    }

    const int hi  = lane >> 5;
    const int ks  = hi * 8;      // k-slice start for A/B frags
    const int hi4 = hi * 4;      // acc row offset 4*(lane>>5)

    // ---- A-frags (centers), 3-way bf16 split, resident: row=lane&31, k=ks+j ----
    short8 a_h[2], a_m[2], a_l[2];
    #pragma unroll
    for (int tc = 0; tc < 2; ++tc) {
        const float* cp = co + (tc * 32 + (lane & 31)) * D + ks;
        float4 v0 = *(const float4*)cp;
        float4 v1 = *(const float4*)(cp + 4);
        float vv[8] = {v0.x,v0.y,v0.z,v0.w, v1.x,v1.y,v1.z,v1.w};
        #pragma unroll
        for (int j = 0; j < 8; ++j) {
            float v = vv[j];
            unsigned h = f2bf(v); float r1 = v - bf2f(h);
            unsigned m = f2bf(r1); r1 = r1 - bf2f(m);
            unsigned l2 = f2bf(r1);
            a_h[tc][j] = (short)h; a_m[tc][j] = (short)m; a_l[tc][j] = (short)l2;
        }
    }
    __syncthreads();

    const int S0 = vb * (BLOCK * NPT) + wave * 64;   // pass-0 tile base
    const int S1 = S0 + BLOCK;                       // pass-1 tile base
    const int l31 = lane & 31;

    // ---- Prologue: x1 loads for pass 0 ----
    int P00 = S0 + l31;        P00 = P00 < n ? P00 : n - 1;
    int P01 = S0 + 32 + l31;   P01 = P01 < n ? P01 : n - 1;
    const float* a0p = x + (size_t)P00 * 32 + ks;
    const float* a1p = x + (size_t)P01 * 32 + ks;
    float4 c00 = *(const float4*)a0p, c01 = *(const float4*)(a0p + 4);
    float4 c10 = *(const float4*)a1p, c11 = *(const float4*)(a1p + 4);

    // ================= pass 0 =================
    {
        const int p = S0 + lane;
        const int q = p < n ? p : n - 1;
        const float4* yp = (const float4*)(x + (size_t)q * 32 + 16);   // x2, issued early
        float4 ya = yp[0], yb = yp[1], yc = yp[2], yd = yp[3];

        short8 bh0, bm0, bl0, bh1, bm1, bl1;
        conv_pt(c00, c01, &bh0, &bm0, &bl0);
        conv_pt(c10, c11, &bh1, &bm1, &bl1);

        // ---- prefetch pass-1 x1 ----
        int Q0 = S1 + l31;        Q0 = Q0 < n ? Q0 : n - 1;
        int Q1 = S1 + 32 + l31;   Q1 = Q1 < n ? Q1 : n - 1;
        const float* b0p = x + (size_t)Q0 * 32 + ks;
        const float* b1p = x + (size_t)Q1 * 32 + ks;
        float4 n00 = *(const float4*)b0p, n01 = *(const float4*)(b0p + 4);
        float4 n10 = *(const float4*)b1p, n11 = *(const float4*)(b1p + 4);

        int bo0 = mfma_scan(a_h, a_m, a_l, bh0, bm0, bl0, s_onorm, hi4);
        int bo1 = mfma_scan(a_h, a_m, a_l, bh1, bm1, bl1, s_onorm, hi4);
        int bo  = (lane < 32) ? bo0 : bo1;

        float x2[16] = {ya.x,ya.y,ya.z,ya.w, yb.x,yb.y,yb.z,yb.w,
                        yc.x,yc.y,yc.z,yc.w, yd.x,yd.y,yd.z,yd.w};
        int bk = inner_argmin(s_ci, s_inorm, bo, x2);
        if (p < n) out[p] = bo * NCPC + bk;

        c00 = n00; c01 = n01; c10 = n10; c11 = n11;   // hand off to pass 1
    }
    // ================= pass 1 =================
    {
        const int p = S1 + lane;
        const int q = p < n ? p : n - 1;
        const float4* yp = (const float4*)(x + (size_t)q * 32 + 16);
        float4 ya = yp[0], yb = yp[1], yc = yp[2], yd = yp[3];

        short8 bh0, bm0, bl0, bh1, bm1, bl1;
        conv_pt(c00, c01, &bh0, &bm0, &bl0);
        conv_pt(c10, c11, &bh1, &bm1, &bl1);

        int bo0 = mfma_scan(a_h, a_m, a_l, bh0, bm0, bl0, s_onorm, hi4);
        int bo1 = mfma_scan(a_h, a_m, a_l, bh1, bm1, bl1, s_onorm, hi4);
        int bo  = (lane < 32) ? bo0 : bo1;

        float x2[16] = {ya.x,ya.y,ya.z,ya.w, yb.x,yb.y,yb.z,yb.w,
                        yc.x,yc.y,yc.z,yc.w, yd.x,yd.y,yd.z,yd.w};
        int bk = inner_argmin(s_ci, s_inorm, bo, x2);
        if (p < n) out[p] = bo * NCPC + bk;
    }
}

extern "C" void kernel_launch(void* const* d_in, const int* in_sizes, int n_in,
                              void* d_out, int out_size, void* d_ws, size_t ws_size,
                              hipStream_t stream) {
    const float* x  = (const float*)d_in[0];   // (N, 32) fp32
    const float* co = (const float*)d_in[1];   // (64, 16) fp32
    const float* ci = (const float*)d_in[2];   // (64, 8, 16) fp32
    int* out = (int*)d_out;                    // (N,) int32
    int n = in_sizes[0] / 32;
    int nb = (n + BLOCK * NPT - 1) / (BLOCK * NPT);
    // Diagnostic: 2x grid, second half duplicates the first (identical writes).
    cluster_kernel<<<nb * 2, BLOCK, 0, stream>>>(x, co, ci, out, n, nb);
}

// Round 12
// 189.340 us; speedup vs baseline: 1.1335x; 1.1335x over previous
//
#include <hip/hip_runtime.h>

// N=1e6, D1=D2=16, NC=64 outer, NCPC=8 inner.
// R12: R11 counters showed latency-bound w/ idle pipes (VALU 43%, MFMA 11%, HBM 21%,
// 2x work = +33% time) at 16 waves/CU (BLOCK=256 x 4 blocks LDS-capped). Fix:
// BLOCK=512 keeps 4 blocks/CU (same 36.3KB LDS/block) but 32 waves/CU = 8/SIMD.
// VGPR precondition measured: compiler fit the fatter R11 body in exactly 64 VGPR
// no-spill; launch_bounds(512,4) caps at 2048/32 = 64. Body: single pass (NPT=1,
// prefetch dropped - proven neutral in R10), arithmetic bit-identical to R10.
constexpr int D = 16;
constexpr int NC = 64;
constexpr int NCPC = 8;
constexpr int OSTRIDE = NCPC * D + 4;   // 132 floats
constexpr int BLOCK = 512;              // 8 waves/block, 512 pts/block

typedef __attribute__((ext_vector_type(8)))  short short8;
typedef __attribute__((ext_vector_type(16))) float f32x16;

static __device__ __forceinline__ unsigned f2bf(float f) {   // RNE fp32->bf16 bits
    unsigned u = __float_as_uint(f);
    u += 0x7FFFu + ((u >> 16) & 1u);
    return u >> 16;
}
static __device__ __forceinline__ float bf2f(unsigned h) {
    return __uint_as_float(h << 16);
}

// 3-way bf16 split of (-2 * x) for one 8-element k-slice.
static __device__ __forceinline__ void conv_pt(float4 w0, float4 w1,
                                               short8* bh, short8* bm, short8* bl) {
    float vv[8] = {w0.x,w0.y,w0.z,w0.w, w1.x,w1.y,w1.z,w1.w};
    #pragma unroll
    for (int j = 0; j < 8; ++j) {
        float v = -2.0f * vv[j];           // exact (power of two)
        unsigned h = f2bf(v); float r1 = v - bf2f(h);
        unsigned m = f2bf(r1); r1 = r1 - bf2f(m);
        unsigned l2 = f2bf(r1);
        (*bh)[j] = (short)h; (*bm)[j] = (short)m; (*bl)[j] = (short)l2;
    }
}

// MFMA distance + within-lane argmin + cross-half merge for one 32-point tile.
static __device__ __forceinline__ int mfma_scan(const short8* a_h, const short8* a_m,
                                                const short8* a_l,
                                                short8 bh, short8 bm, short8 bl,
                                                const float* s_onorm, int hi4) {
    float bestd = 3.4e38f; int bc = 0;
    #pragma unroll
    for (int tc = 0; tc < 2; ++tc) {
        f32x16 acc;
        #pragma unroll
        for (int g = 0; g < 4; ++g) {       // acc init = outer norms (broadcast ds_read)
            float4 nn = *(const float4*)&s_onorm[tc * 32 + g * 8 + hi4];
            acc[g*4+0] = nn.x; acc[g*4+1] = nn.y; acc[g*4+2] = nn.z; acc[g*4+3] = nn.w;
        }
        acc = __builtin_amdgcn_mfma_f32_32x32x16_bf16(a_h[tc], bh, acc, 0,0,0);
        acc = __builtin_amdgcn_mfma_f32_32x32x16_bf16(a_h[tc], bm, acc, 0,0,0);
        acc = __builtin_amdgcn_mfma_f32_32x32x16_bf16(a_m[tc], bh, acc, 0,0,0);
        acc = __builtin_amdgcn_mfma_f32_32x32x16_bf16(a_h[tc], bl, acc, 0,0,0);
        acc = __builtin_amdgcn_mfma_f32_32x32x16_bf16(a_m[tc], bm, acc, 0,0,0);
        acc = __builtin_amdgcn_mfma_f32_32x32x16_bf16(a_l[tc], bh, acc, 0,0,0);
        #pragma unroll
        for (int r = 0; r < 16; ++r) {      // increasing-index scan, strict <
            float d = acc[r];
            int  c = tc * 32 + (r & 3) + 8 * (r >> 2);
            if (d < bestd) { bestd = d; bc = c; }
        }
    }
    int bestc = bc + hi4;
    int lane = (int)(threadIdx.x & 63);
    int pidx = (lane ^ 32) << 2;
    float od = __int_as_float(
        __builtin_amdgcn_ds_bpermute(pidx, __float_as_int(bestd)));
    int   oc = __builtin_amdgcn_ds_bpermute(pidx, bestc);
    if (od < bestd || (od == bestd && oc < bestc)) bestc = oc;
    return bestc;
}

// Inner argmin over bo's 8 sub-centers (LDS gather). Unchanged arithmetic.
static __device__ __forceinline__ int inner_argmin(const float* s_ci,
                                                   const float* s_inorm,
                                                   int bo, const float* x2) {
    const float* cb = s_ci + bo * OSTRIDE;
    const float* nb = s_inorm + bo * 9;
    float bestd2 = 3.4e38f;
    int bk = 0;
    #pragma unroll
    for (int k = 0; k < NCPC; ++k) {
        float4 e0 = *(const float4*)&cb[k * D + 0];
        float4 e1 = *(const float4*)&cb[k * D + 4];
        float4 e2 = *(const float4*)&cb[k * D + 8];
        float4 e3 = *(const float4*)&cb[k * D + 12];
        float dot = 0.f;
        dot = fmaf(x2[0],  e0.x, dot); dot = fmaf(x2[1],  e0.y, dot);
        dot = fmaf(x2[2],  e0.z, dot); dot = fmaf(x2[3],  e0.w, dot);
        dot = fmaf(x2[4],  e1.x, dot); dot = fmaf(x2[5],  e1.y, dot);
        dot = fmaf(x2[6],  e1.z, dot); dot = fmaf(x2[7],  e1.w, dot);
        dot = fmaf(x2[8],  e2.x, dot); dot = fmaf(x2[9],  e2.y, dot);
        dot = fmaf(x2[10], e2.z, dot); dot = fmaf(x2[11], e2.w, dot);
        dot = fmaf(x2[12], e3.x, dot); dot = fmaf(x2[13], e3.y, dot);
        dot = fmaf(x2[14], e3.z, dot); dot = fmaf(x2[15], e3.w, dot);
        float d2v = fmaf(-2.f, dot, nb[k]);
        if (d2v < bestd2) { bestd2 = d2v; bk = k; }
    }
    return bk;
}

__global__ __launch_bounds__(BLOCK, 4)   // 4 blocks/CU (LDS-capped) -> 32 waves/CU,
void cluster_kernel(const float* __restrict__ x,      // VGPR cap 64 (measured fit)
                    const float* __restrict__ co,
                    const float* __restrict__ ci,
                    int* __restrict__ out, int n)
{
    __shared__ __align__(16) float s_ci[NC * OSTRIDE];   // 33792 B
    __shared__ __align__(16) float s_onorm[NC];          // 256 B
    __shared__ float s_inorm[NC * 9];                    // 2304 B

    const int t    = threadIdx.x;
    const int lane = t & 63;
    const int wave = t >> 6;

    // ---- Stage inner centers (2048 float4, 4 per thread) ----
    const float4* ci4 = (const float4*)ci;
    #pragma unroll
    for (int i = 0; i < 4; ++i) {
        int idx = t + i * BLOCK;
        int o = idx >> 5, f = idx & 31;
        float4 v = ci4[idx];
        *(float4*)&s_ci[o * OSTRIDE + f * 4] = v;
    }
    // ---- 512 inner norms, one per thread ----
    {
        int i = t;
        const float* src = ci + i * D;
        float s = 0.f;
        #pragma unroll
        for (int k = 0; k < D; ++k) s = fmaf(src[k], src[k], s);
        s_inorm[(i >> 3) * 9 + (i & 7)] = s;
    }
    // ---- 64 outer norms -> LDS ----
    if (t < NC) {
        const float* c = co + t * D;
        float s = 0.f;
        #pragma unroll
        for (int k = 0; k < D; ++k) s = fmaf(c[k], c[k], s);
        s_onorm[t] = s;
    }

    const int hi  = lane >> 5;
    const int ks  = hi * 8;      // k-slice start for A/B frags
    const int hi4 = hi * 4;      // acc row offset 4*(lane>>5)

    // ---- A-frags (centers), 3-way bf16 split, resident: row=lane&31, k=ks+j ----
    short8 a_h[2], a_m[2], a_l[2];
    #pragma unroll
    for (int tc = 0; tc < 2; ++tc) {
        const float* cp = co + (tc * 32 + (lane & 31)) * D + ks;
        float4 v0 = *(const float4*)cp;
        float4 v1 = *(const float4*)(cp + 4);
        float vv[8] = {v0.x,v0.y,v0.z,v0.w, v1.x,v1.y,v1.z,v1.w};
        #pragma unroll
        for (int j = 0; j < 8; ++j) {
            float v = vv[j];
            unsigned h = f2bf(v); float r1 = v - bf2f(h);
            unsigned m = f2bf(r1); r1 = r1 - bf2f(m);
            unsigned l2 = f2bf(r1);
            a_h[tc][j] = (short)h; a_m[tc][j] = (short)m; a_l[tc][j] = (short)l2;
        }
    }
    __syncthreads();

    // ---- Single pass: wave's 64 points ----
    const int S   = blockIdx.x * BLOCK + wave * 64;
    const int l31 = lane & 31;

    // x1 loads for both 32-point tiles of this wave
    int P0 = S + l31;        P0 = P0 < n ? P0 : n - 1;
    int P1 = S + 32 + l31;   P1 = P1 < n ? P1 : n - 1;
    const float* a0p = x + (size_t)P0 * 32 + ks;
    const float* a1p = x + (size_t)P1 * 32 + ks;
    float4 c00 = *(const float4*)a0p, c01 = *(const float4*)(a0p + 4);
    float4 c10 = *(const float4*)a1p, c11 = *(const float4*)(a1p + 4);

    // x2 for own point, issued early (address bo-independent)
    const int p = S + lane;
    const int q = p < n ? p : n - 1;
    const float4* yp = (const float4*)(x + (size_t)q * 32 + 16);
    float4 ya = yp[0], yb = yp[1], yc = yp[2], yd = yp[3];

    short8 bh0, bm0, bl0, bh1, bm1, bl1;
    conv_pt(c00, c01, &bh0, &bm0, &bl0);
    conv_pt(c10, c11, &bh1, &bm1, &bl1);

    int bo0 = mfma_scan(a_h, a_m, a_l, bh0, bm0, bl0, s_onorm, hi4);
    int bo1 = mfma_scan(a_h, a_m, a_l, bh1, bm1, bl1, s_onorm, hi4);
    int bo  = (lane < 32) ? bo0 : bo1;

    float x2[16] = {ya.x,ya.y,ya.z,ya.w, yb.x,yb.y,yb.z,yb.w,
                    yc.x,yc.y,yc.z,yc.w, yd.x,yd.y,yd.z,yd.w};
    int bk = inner_argmin(s_ci, s_inorm, bo, x2);
    if (p < n) out[p] = bo * NCPC + bk;
}

extern "C" void kernel_launch(void* const* d_in, const int* in_sizes, int n_in,
                              void* d_out, int out_size, void* d_ws, size_t ws_size,
                              hipStream_t stream) {
    const float* x  = (const float*)d_in[0];   // (N, 32) fp32
    const float* co = (const float*)d_in[1];   // (64, 16) fp32
    const float* ci = (const float*)d_in[2];   // (64, 8, 16) fp32
    int* out = (int*)d_out;                    // (N,) int32
    int n = in_sizes[0] / 32;
    int blocks = (n + BLOCK - 1) / BLOCK;      // 1954
    cluster_kernel<<<blocks, BLOCK, 0, stream>>>(x, co, ci, out, n);
}